// Round 7
// baseline (99.821 us; speedup 1.0000x reference)
//
#include <hip/hip_runtime.h>

#define BB 256
#define SS 512
#define DD 64
#define LN_EPS 1e-5f
#define L2E 1.4426950408889634f
#define NN 16            // Chebyshev nodes per task
#define PI_F 3.14159265358979f

__device__ __forceinline__ float fexp2(float x) {
#if __has_builtin(__builtin_amdgcn_exp2f)
    return __builtin_amdgcn_exp2f(x);
#else
    float r; asm("v_exp_f32 %0, %1" : "=v"(r) : "v"(x)); return r;
#endif
}

// ONE kernel, 256 blocks (one per batch), 512 threads, all 3 tasks per block.
// Algebra: h = x*pw + pb (rank-1+const) =>
//   attn[q,k] = softmax_k(c_q*y_k), c_q = alpha*x_q + gamma
//   r_q = x_q*pw + t_q*u + e, t_q = sum_k attn*y_k (scalar), t = f'(c)/f(c)
//   t(c) fit by 16-node Chebyshev on the block's exact c-range (exact exp at
//   nodes), per-query Clenshaw. LN closed-form via 3x3 Gram of centered
//   {pw,u,e}; seq-mean needs only P=mean(x*inv), T=mean(t*inv), I=mean(inv).
// tasks: 0: sa,x=xs,y=xs -> z_src_private@B*D | 1: sa,x=xt,y=xt -> z_tgt@2B*D
//        2: ca,x=xs,y=xt -> z_shared@0
__global__ __launch_bounds__(512) void fused_all(
    const float* __restrict__ x_src, const float* __restrict__ x_tgt,
    const float* __restrict__ proj_w, const float* __restrict__ proj_b,
    const float* __restrict__ sa_in_w, const float* __restrict__ sa_in_b,
    const float* __restrict__ sa_out_w, const float* __restrict__ sa_out_b,
    const float* __restrict__ sa_ln_g, const float* __restrict__ sa_ln_b,
    const float* __restrict__ ca_in_w, const float* __restrict__ ca_in_b,
    const float* __restrict__ ca_out_w, const float* __restrict__ ca_out_b,
    const float* __restrict__ ca_ln_g, const float* __restrict__ ca_ln_b,
    float* __restrict__ out)
{
    const int tid  = threadIdx.x;
    const int b    = blockIdx.x;
    const int wave = tid >> 6, lane = tid & 63;

    __shared__ __align__(16) float xs_l[SS];
    __shared__ __align__(16) float xt_l[SS];
    __shared__ float sv[2][6][DD];       // aq,ak,av,cq,ck,cv per type
    __shared__ float cw[2][3][DD];       // centered pw/u/e per type ([1],[2] park u,e)
    __shared__ float cst[2][8];          // alpha,gamma,G11,G22,G33,G12,G13,G23
    __shared__ float rmx[8][4];          // per-wave xs_mx, xs_mn, xt_mx, xt_mn
    __shared__ float bb4[4];             // block xs_mx, xs_mn, xt_mx, xt_mn
    __shared__ float tj_l[3 * NN];
    __shared__ float ac_l[3 * NN];
    __shared__ float rpti[8][9];
    __shared__ float ptio[9];            // {P,T,I} x 3 tasks

    // ---- phase A: load x rows, per-wave min/max ----
    const float xs = x_src[b * SS + tid];
    const float xt = x_tgt[b * SS + tid];
    xs_l[tid] = xs; xt_l[tid] = xt;
    {
        float sx = xs, sn = xs, tx = xt, tn = xt;
        #pragma unroll
        for (int o = 32; o > 0; o >>= 1) {
            sx = fmaxf(sx, __shfl_down(sx, o));
            sn = fminf(sn, __shfl_down(sn, o));
            tx = fmaxf(tx, __shfl_down(tx, o));
            tn = fminf(tn, __shfl_down(tn, o));
        }
        if (lane == 0) { rmx[wave][0] = sx; rmx[wave][1] = sn;
                         rmx[wave][2] = tx; rmx[wave][3] = tn; }
    }

    // ---- stage 1: 12 matvecs {q,k,v} x {pw,pb} x {sa,ca}; wave w -> mats w, w+8
    for (int m = wave; m < 12; m += 8) {
        const int type = m / 6, which = m % 6;
        const int rb = which % 3, vecsel = which / 3;
        const float* W = (type ? ca_in_w : sa_in_w) + (rb * DD + lane) * DD;
        const float* v = vecsel ? proj_b : proj_w;
        float s = 0.f;
        #pragma unroll
        for (int e = 0; e < DD; e += 4) {
            float4 wv = *(const float4*)(W + e);
            float4 vv = *(const float4*)(v + e);
            s += wv.x * vv.x + wv.y * vv.y + wv.z * vv.z + wv.w * vv.w;
        }
        if (vecsel) s += (type ? ca_in_b : sa_in_b)[rb * DD + lane];
        sv[type][which][lane] = s;
    }
    __syncthreads();

    // ---- stage 2: u = Wo@av ; e = pb + Wo@cv + bo (waves 0-3) ----
    if (wave < 4) {
        const int type = wave >> 1, which = wave & 1;
        const float* W = (type ? ca_out_w : sa_out_w) + lane * DD;
        const float* v = sv[type][which ? 5 : 2];     // cv : av
        float s = 0.f;
        #pragma unroll
        for (int e = 0; e < DD; e += 4) {
            float4 wv = *(const float4*)(W + e);
            s += wv.x * v[e] + wv.y * v[e + 1] + wv.z * v[e + 2] + wv.w * v[e + 3];
        }
        if (which) cw[type][2][lane] = proj_b[lane] + s + (type ? ca_out_b : sa_out_b)[lane];
        else       cw[type][1][lane] = s;
    }
    if (tid == 511) {
        float a = rmx[0][0], m = rmx[0][1], c = rmx[0][2], d = rmx[0][3];
        #pragma unroll
        for (int i = 1; i < 8; ++i) {
            a = fmaxf(a, rmx[i][0]); m = fminf(m, rmx[i][1]);
            c = fmaxf(c, rmx[i][2]); d = fminf(d, rmx[i][3]);
        }
        bb4[0] = a; bb4[1] = m; bb4[2] = c; bb4[3] = d;
    }
    __syncthreads();

    // ---- stage 3: scalars + Gram + centering (wave w = type w) ----
    if (wave < 2) {
        const int type = wave;
        auto wred = [](float x) {
            #pragma unroll
            for (int o = 32; o > 0; o >>= 1) x += __shfl_down(x, o);
            return __shfl(x, 0);
        };
        const float aq = sv[type][0][lane], ak = sv[type][1][lane];
        const float cq = sv[type][3][lane];
        const float pw = proj_w[lane];
        const float u  = cw[type][1][lane], e = cw[type][2][lane];

        const float alpha = wred(aq * ak) * 0.125f;   // /sqrt(64)
        const float gamma = wred(cq * ak) * 0.125f;
        const float m_pw = wred(pw) * (1.f / DD);
        const float m_u  = wred(u)  * (1.f / DD);
        const float m_e  = wred(e)  * (1.f / DD);
        const float a  = pw - m_pw;
        const float bbv = u - m_u;
        const float c  = e  - m_e;
        const float G11 = wred(a * a)     * (1.f / DD);
        const float G22 = wred(bbv * bbv) * (1.f / DD);
        const float G33 = wred(c * c)     * (1.f / DD);
        const float G12 = wred(a * bbv)   * (1.f / DD);
        const float G13 = wred(a * c)     * (1.f / DD);
        const float G23 = wred(bbv * c)   * (1.f / DD);

        cw[type][0][lane] = a; cw[type][1][lane] = bbv; cw[type][2][lane] = c;
        if (lane == 0) {
            cst[type][0] = alpha; cst[type][1] = gamma;
            cst[type][2] = G11; cst[type][3] = G22; cst[type][4] = G33;
            cst[type][5] = G12; cst[type][6] = G13; cst[type][7] = G23;
        }
    }
    __syncthreads();

    // per-task geometry (lane-uniform helpers)
    const float xsmx = bb4[0], xsmn = bb4[1], xtmx = bb4[2], xtmn = bb4[3];
    float mid_[3], hw_[3], ymx_[3], ymn_[3];
    #pragma unroll
    for (int task = 0; task < 3; ++task) {
        const int ty = (task == 2) ? 1 : 0;
        const float al = cst[ty][0], ga = cst[ty][1];
        const float xlo = (task == 1) ? xtmn : xsmn;
        const float xhi = (task == 1) ? xtmx : xsmx;
        const float cA = al * xlo + ga, cB = al * xhi + ga;
        const float lo = fminf(cA, cB), hi = fmaxf(cA, cB);
        mid_[task] = 0.5f * (lo + hi);
        hw_[task]  = fmaxf(0.5f * (hi - lo), 1e-6f);
        ymx_[task] = (task == 0) ? xsmx : xtmx;
        ymn_[task] = (task == 0) ? xsmn : xtmn;
    }

    // ---- node eval: 48 nodes (3 tasks x 16); wave w -> nodes 6w..6w+5, paired
    #pragma unroll
    for (int p = 0; p < 3; ++p) {
        const int n0 = 6 * wave + 2 * p, n1 = n0 + 1;
        const int tk0 = n0 >> 4, j0 = n0 & 15;
        const int tk1 = n1 >> 4, j1 = n1 & 15;
        const float cj0 = mid_[tk0] + hw_[tk0] * __cosf(PI_F * (j0 + 0.5f) * (1.f / NN));
        const float cj1 = mid_[tk1] + hw_[tk1] * __cosf(PI_F * (j1 + 0.5f) * (1.f / NN));
        const float c0l = cj0 * L2E, c1l = cj1 * L2E;
        const float s0 = fmaxf(c0l * ymx_[tk0], c0l * ymn_[tk0]);
        const float s1 = fmaxf(c1l * ymx_[tk1], c1l * ymn_[tk1]);
        const float* y0b = (tk0 == 0) ? xs_l : xt_l;
        const float* y1b = (tk1 == 0) ? xs_l : xt_l;
        float S00 = 0.f, S10 = 0.f, S01 = 0.f, S11 = 0.f;
        #pragma unroll
        for (int i = 0; i < 8; ++i) {
            const float ya = y0b[lane + (i << 6)];
            const float yb = y1b[lane + (i << 6)];
            const float e0 = fexp2(c0l * ya - s0);
            const float e1 = fexp2(c1l * yb - s1);
            S00 += e0; S10 += ya * e0;
            S01 += e1; S11 += yb * e1;
        }
        #pragma unroll
        for (int o = 32; o > 0; o >>= 1) {
            S00 += __shfl_down(S00, o); S10 += __shfl_down(S10, o);
            S01 += __shfl_down(S01, o); S11 += __shfl_down(S11, o);
        }
        if (lane == 0) { tj_l[n0] = S10 / S00; tj_l[n1] = S11 / S01; }
    }
    __syncthreads();

    // ---- DCT -> Chebyshev coefficients (tid < 48) ----
    if (tid < 3 * NN) {
        const int task = tid >> 4, k = tid & 15;
        const float* tj = &tj_l[task * NN];
        float acc = 0.f;
        #pragma unroll
        for (int j = 0; j < NN; ++j)
            acc += tj[j] * __cosf(PI_F * k * (j + 0.5f) * (1.f / NN));
        float a = acc * (2.f / NN);
        if (k == 0) a *= 0.5f;          // store a0/2
        ac_l[tid] = a;
    }
    __syncthreads();

    // ---- 3 interleaved Clenshaws + LN stats ----
    const float xq0 = xs, xq1 = xt, xq2 = xs;
    float xi0 = (cst[0][0] * xq0 + cst[0][1] - mid_[0]) / hw_[0];
    float xi1 = (cst[0][0] * xq1 + cst[0][1] - mid_[1]) / hw_[1];
    float xi2 = (cst[1][0] * xq2 + cst[1][1] - mid_[2]) / hw_[2];
    xi0 = fminf(1.f, fmaxf(-1.f, xi0));
    xi1 = fminf(1.f, fmaxf(-1.f, xi1));
    xi2 = fminf(1.f, fmaxf(-1.f, xi2));
    const float u0 = 2.f * xi0, u1 = 2.f * xi1, u2 = 2.f * xi2;
    float b10 = 0.f, b20 = 0.f, b11 = 0.f, b21 = 0.f, b12 = 0.f, b22 = 0.f;
    #pragma unroll
    for (int k = NN - 1; k >= 1; --k) {
        const float a0 = ac_l[k], a1 = ac_l[NN + k], a2 = ac_l[2 * NN + k];
        const float n0 = fmaf(u0, b10, a0 - b20); b20 = b10; b10 = n0;
        const float n1 = fmaf(u1, b11, a1 - b21); b21 = b11; b11 = n1;
        const float n2 = fmaf(u2, b12, a2 - b22); b22 = b12; b12 = n2;
    }
    const float t0 = fmaf(xi0, b10, ac_l[0] - b20);
    const float t1 = fmaf(xi1, b11, ac_l[NN] - b21);
    const float t2 = fmaf(xi2, b12, ac_l[2 * NN] - b22);

    float pv[9];
    {
        const float* G = cst[0];
        float var0 = xq0 * xq0 * G[2] + t0 * t0 * G[3] + G[4]
                   + 2.f * (xq0 * t0 * G[5] + xq0 * G[6] + t0 * G[7]);
        float var1 = xq1 * xq1 * G[2] + t1 * t1 * G[3] + G[4]
                   + 2.f * (xq1 * t1 * G[5] + xq1 * G[6] + t1 * G[7]);
        const float* H = cst[1];
        float var2 = xq2 * xq2 * H[2] + t2 * t2 * H[3] + H[4]
                   + 2.f * (xq2 * t2 * H[5] + xq2 * H[6] + t2 * H[7]);
        const float i0 = rsqrtf(var0 + LN_EPS);
        const float i1 = rsqrtf(var1 + LN_EPS);
        const float i2 = rsqrtf(var2 + LN_EPS);
        pv[0] = xq0 * i0; pv[1] = t0 * i0; pv[2] = i0;
        pv[3] = xq1 * i1; pv[4] = t1 * i1; pv[5] = i1;
        pv[6] = xq2 * i2; pv[7] = t2 * i2; pv[8] = i2;
    }
    #pragma unroll
    for (int o = 32; o > 0; o >>= 1) {
        #pragma unroll
        for (int q = 0; q < 9; ++q) pv[q] += __shfl_down(pv[q], o);
    }
    if (lane == 0) {
        #pragma unroll
        for (int q = 0; q < 9; ++q) rpti[wave][q] = pv[q];
    }
    __syncthreads();
    if (tid < 9) {
        float s = 0.f;
        #pragma unroll
        for (int i = 0; i < 8; ++i) s += rpti[i][tid];
        ptio[tid] = s * (1.f / SS);
    }
    __syncthreads();

    // ---- epilogue: 3 x 64 outputs ----
    if (tid < 3 * DD) {
        const int task = tid >> 6, d = tid & 63;
        const int ty = (task == 2) ? 1 : 0;
        const float P = ptio[3 * task], T = ptio[3 * task + 1], I = ptio[3 * task + 2];
        const float* g  = ty ? ca_ln_g : sa_ln_g;
        const float* lb = ty ? ca_ln_b : sa_ln_b;
        const int base = (task == 0) ? BB * DD : (task == 1) ? 2 * BB * DD : 0;
        const float z = (P * cw[ty][0][d] + T * cw[ty][1][d] + I * cw[ty][2][d]) * g[d] + lb[d];
        out[base + b * DD + d] = z;
    }
}

extern "C" void kernel_launch(void* const* d_in, const int* in_sizes, int n_in,
                              void* d_out, int out_size, void* d_ws, size_t ws_size,
                              hipStream_t stream) {
    const float* x_src    = (const float*)d_in[0];
    const float* x_tgt    = (const float*)d_in[1];
    const float* proj_w   = (const float*)d_in[2];
    const float* proj_b   = (const float*)d_in[3];
    const float* sa_in_w  = (const float*)d_in[4];
    const float* sa_in_b  = (const float*)d_in[5];
    const float* sa_out_w = (const float*)d_in[6];
    const float* sa_out_b = (const float*)d_in[7];
    const float* sa_ln_g  = (const float*)d_in[8];
    const float* sa_ln_b  = (const float*)d_in[9];
    const float* ca_in_w  = (const float*)d_in[10];
    const float* ca_in_b  = (const float*)d_in[11];
    const float* ca_out_w = (const float*)d_in[12];
    const float* ca_out_b = (const float*)d_in[13];
    const float* ca_ln_g  = (const float*)d_in[14];
    const float* ca_ln_b  = (const float*)d_in[15];
    float* out = (float*)d_out;

    fused_all<<<BB, 512, 0, stream>>>(
        x_src, x_tgt, proj_w, proj_b,
        sa_in_w, sa_in_b, sa_out_w, sa_out_b, sa_ln_g, sa_ln_b,
        ca_in_w, ca_in_b, ca_out_w, ca_out_b, ca_ln_g, ca_ln_b,
        out);
}